// Round 11
// baseline (196.921 us; speedup 1.0000x reference)
//
#include <hip/hip_runtime.h>
#include <hip/hip_bf16.h>

// MILAttentionPool: B=32, L=2048, D=512, H=256, K=4
// out[b, k*512+d] = sum_l softmax_l(logit[b,l,k]) * x[b*L+l, d]
// logit = (tanh(x@W1+b1)*sigmoid(x@W3+b3)) @ W2   (+b2 cancels in softmax)
//
// R11: persistent pipelined blocks to keep HBM saturated (R10 ran HBM at 9%
// because stage/GEMM/pool phases serialized with HBM idle outside staging).
// 256 blocks x 512 thr, 1 block/CU, 4 tiles of 64 rows each, LDS x dbuf
// (2x64KB). Next tile's 256B/thread loaded to REGISTERS before GEMM (issue
// pinned with sched_barrier) -> the epilogue barrier's vmcnt drain overlaps
// compute; cvt+ds_write after pooling. GEMM/pool layouts = R10 (0 conflicts).

typedef short  bf16x8 __attribute__((ext_vector_type(8)));
typedef float  f32x4  __attribute__((ext_vector_type(4)));

#define D_IN    512
#define H_DIM   256
#define L_BAG   2048

__device__ __forceinline__ short f2bf(float f) {
  union { __hip_bfloat16 h; short s; } u;
  u.h = __float2bfloat16(f);
  return u.s;
}
__device__ __forceinline__ float bf2f(short s) {
  union { float f; unsigned u; } u;
  u.u = ((unsigned)(unsigned short)s) << 16;
  return u.f;
}

// ---------------- k0: concat-interleaved, chunk-major bf16 weights ----------------
// wc short idx = kt*16384 + (c*512 + n_c)*8 + r   (k = kt*32 + c*8 + r)
//   n_c: g=n_c>>5, j=n_c&31; j<16 -> W1[:, g*16+j] else W3[:, g*16+j-16]
__global__ __launch_bounds__(256) void k_prep_w(const float* __restrict__ W1,
                                                const float* __restrict__ W3,
                                                short* __restrict__ wc) {
  int t = blockIdx.x * 256 + threadIdx.x;   // 0..32767
  int n_c = t & 511;
  int kc  = t >> 9;            // k-chunk of 8: 0..63
  int kt = kc >> 2, c = kc & 3;
  int g = n_c >> 5, j = n_c & 31;
  const float* src = (j < 16) ? W1 : W3;
  int h = g * 16 + (j & 15);
  bf16x8 v;
  #pragma unroll
  for (int r = 0; r < 8; ++r) v[r] = f2bf(src[(kc * 8 + r) * H_DIM + h]);
  *(bf16x8*)(wc + kt * 16384 + (c * 512 + n_c) * 8) = v;
}

// ---------------- k1: persistent fused stage+GEMM+gate@W2+exp+pool ----------------
__global__ __launch_bounds__(512, 2) void k_fused(
    const float* __restrict__ x,
    const short* __restrict__ wc,
    const float* __restrict__ b1, const float* __restrict__ b3,
    const float* __restrict__ W2,
    short* __restrict__ part, float* __restrict__ psumP)
{
  __shared__ __align__(16) short xbf[2][64 * 512];  // 2 x 64 KB, chunk-major [kc][row][8]
  __shared__ float lpart[8][64][4];                 //  8 KB
  __shared__ __align__(16) float wlds[64 * 4];      //  1 KB
  __shared__ float psc[4][4];                       // (total ~140 KB -> 1 block/CU)

  const int tid  = threadIdx.x;
  const int lane = tid & 63;
  const int w    = tid >> 6;
  const int l15  = lane & 15;
  const int q    = lane >> 4;
  const int blk  = blockIdx.x;      // 0..255

  const int r   = tid & 63;         // staging row
  const int kc0 = (tid >> 6) * 8;   // staging k-chunk base

  float4 xf[16];                    // next-tile prefetch (statically indexed)

#define XLOAD(tile) { \
    const float* xr_ = x + ((long)(tile) * 64 + r) * D_IN + kc0 * 8; \
    _Pragma("unroll") \
    for (int j_ = 0; j_ < 8; ++j_) { \
      xf[2 * j_]     = ((const float4*)(xr_ + j_ * 8))[0]; \
      xf[2 * j_ + 1] = ((const float4*)(xr_ + j_ * 8))[1]; } }

#define XWRITE(buf) { \
    short* xd_ = (short*)&xbf[buf][0]; \
    _Pragma("unroll") \
    for (int j_ = 0; j_ < 8; ++j_) { bf16x8 v_; \
      v_[0] = f2bf(xf[2*j_].x);   v_[1] = f2bf(xf[2*j_].y); \
      v_[2] = f2bf(xf[2*j_].z);   v_[3] = f2bf(xf[2*j_].w); \
      v_[4] = f2bf(xf[2*j_+1].x); v_[5] = f2bf(xf[2*j_+1].y); \
      v_[6] = f2bf(xf[2*j_+1].z); v_[7] = f2bf(xf[2*j_+1].w); \
      *(bf16x8*)&xd_[((kc0 + j_) * 64 + r) * 8] = v_; } }

  const short* bgp = wc + (q * 512 + w * 64 + l15) * 8;

  bf16x8 bp0[2], bp1[2];
#define LDP0(kt) { const short* p_ = bgp + (kt) * 16384; \
    bp0[0] = *(const bf16x8*)(p_);       bp0[1] = *(const bf16x8*)(p_ + 128); }
#define LDP1(kt) { const short* p_ = bgp + (kt) * 16384; \
    bp1[0] = *(const bf16x8*)(p_ + 256); bp1[1] = *(const bf16x8*)(p_ + 384); }

  // ---- prologue: stage tile 0 ----
  XLOAD(blk * 4);
  XWRITE(0);
  __syncthreads();

  #pragma unroll 1
  for (int i = 0; i < 4; ++i) {
    const int cur  = i & 1;
    const int tile = blk * 4 + i;
    const short* xc = &xbf[cur][0];

    if (i < 3) {
      XLOAD(tile + 1);                      // issue next tile's HBM loads NOW
      __builtin_amdgcn_sched_barrier(0);    // pin issue before the GEMM
    }

    // ---- GEMM: acc[mf 4][nf 4]; B from L2 as alternating 2-frag pairs ----
    f32x4 acc[4][4];
    #pragma unroll
    for (int mf = 0; mf < 4; ++mf)
      #pragma unroll
      for (int nf = 0; nf < 4; ++nf) acc[mf][nf] = (f32x4){0.f, 0.f, 0.f, 0.f};

    LDP0(0);
    #pragma unroll
    for (int kt = 0; kt < 16; ++kt) {
      LDP1(kt);
      const int ab = (kt * 4 + q) * 512 + l15 * 8;
      bf16x8 af[4];
      #pragma unroll
      for (int mf = 0; mf < 4; ++mf) af[mf] = *(const bf16x8*)&xc[ab + mf * 128];
      #pragma unroll
      for (int mf = 0; mf < 4; ++mf) {
        acc[mf][0] = __builtin_amdgcn_mfma_f32_16x16x32_bf16(af[mf], bp0[0], acc[mf][0], 0, 0, 0);
        acc[mf][1] = __builtin_amdgcn_mfma_f32_16x16x32_bf16(af[mf], bp0[1], acc[mf][1], 0, 0, 0);
      }
      if (kt < 15) LDP0(kt + 1);
      #pragma unroll
      for (int mf = 0; mf < 4; ++mf) {
        acc[mf][2] = __builtin_amdgcn_mfma_f32_16x16x32_bf16(af[mf], bp1[0], acc[mf][2], 0, 0, 0);
        acc[mf][3] = __builtin_amdgcn_mfma_f32_16x16x32_bf16(af[mf], bp1[1], acc[mf][3], 0, 0, 0);
      }
    }

    // ---- epilogue: gate + @W2, per-mf ----
    {
      float b1v[2], b3v[2];
      f32x4 wv[2];
      #pragma unroll
      for (int p = 0; p < 2; ++p) {
        int h = w * 32 + p * 16 + l15;
        b1v[p] = b1[h];
        b3v[p] = b3[h];
        wv[p] = *(const f32x4*)&W2[h * 4];
      }
      #pragma unroll
      for (int mf = 0; mf < 4; ++mf) {
        float pl[4][4];
        #pragma unroll
        for (int j = 0; j < 4; ++j)
          #pragma unroll
          for (int kk = 0; kk < 4; ++kk) pl[j][kk] = 0.f;
        #pragma unroll
        for (int p = 0; p < 2; ++p)
          #pragma unroll
          for (int j = 0; j < 4; ++j) {
            float h1 = acc[mf][2 * p][j]     + b1v[p];
            float h3 = acc[mf][2 * p + 1][j] + b3v[p];
            float th = 1.f - __fdividef(2.f, __expf(2.f * h1) + 1.f);
            float sg = __fdividef(1.f, 1.f + __expf(-h3));
            float g = th * sg;
            pl[j][0] += g * wv[p][0];
            pl[j][1] += g * wv[p][1];
            pl[j][2] += g * wv[p][2];
            pl[j][3] += g * wv[p][3];
          }
        #pragma unroll
        for (int off = 1; off < 16; off <<= 1)
          #pragma unroll
          for (int j = 0; j < 4; ++j)
            #pragma unroll
            for (int kk = 0; kk < 4; ++kk)
              pl[j][kk] += __shfl_xor(pl[j][kk], off);
        if (l15 == 0) {
          #pragma unroll
          for (int j = 0; j < 4; ++j)
            #pragma unroll
            for (int kk = 0; kk < 4; ++kk)
              lpart[w][mf * 16 + q * 4 + j][kk] = pl[j][kk];
        }
      }
    }
    __syncthreads();   // lpart ready (drains vmcnt: XLOAD overlapped by GEMM+epilogue)

    // ---- logits sum, exp (no max: logits ~N(0,0.3)), per-tile psum ----
    if (tid < 256) {
      const int rr = tid >> 2, kk = tid & 3;
      float lg = 0.f;
      #pragma unroll
      for (int ww = 0; ww < 8; ++ww) lg += lpart[ww][rr][kk];
      float e = __expf(lg);
      wlds[rr * 4 + kk] = e;
      float v = e;
      #pragma unroll
      for (int o = 4; o < 64; o <<= 1) v += __shfl_xor(v, o);
      if (lane < 4) psc[tid >> 6][lane] = v;   // lane == kk for lanes 0..3
    }
    __syncthreads();   // wlds + psc ready
    if (tid < 4) psumP[tile * 4 + tid] = psc[0][tid] + psc[1][tid] + psc[2][tid] + psc[3][tid];

    // ---- pooling from LDS (kc-rotated, conflict-free) ----
    {
      const int d  = tid;            // 0..511
      const int kc = d >> 3;
      const int e  = d & 7;
      const short* xcol = &xc[kc * 512 + e];
      float a0 = 0.f, a1 = 0.f, a2 = 0.f, a3 = 0.f;
      #pragma unroll 8
      for (int ii = 0; ii < 64; ++ii) {
        int l = (ii + kc) & 63;
        float xv = bf2f(xcol[l * 8]);
        float4 wv4 = *(const float4*)&wlds[l * 4];
        a0 += wv4.x * xv; a1 += wv4.y * xv; a2 += wv4.z * xv; a3 += wv4.w * xv;
      }
      short* pp = part + (long)tile * 2048 + d;
      pp[0]    = f2bf(a0);
      pp[512]  = f2bf(a1);
      pp[1024] = f2bf(a2);
      pp[1536] = f2bf(a3);
    }

    if (i < 3) XWRITE(cur ^ 1);   // stage next tile into the other buffer
    __syncthreads();              // next buffer ready; wlds/psc free for reuse
  }
}

// ---------------- k2: reduce 32 chunks per bag, divide by sum(exp) ----------------
__global__ __launch_bounds__(256) void k_finalize(const short* __restrict__ part,
                                                  const float* __restrict__ psumP,
                                                  float* __restrict__ out) {
  int idx = blockIdx.x * 256 + threadIdx.x;   // b*2048 + k*512 + d
  int b = idx >> 11, k = (idx >> 9) & 3, d = idx & 511;
  const short* pb = part + ((long)b * 32) * 2048 + k * 512 + d;
  float s = 0.f, ps = 0.f;
  #pragma unroll
  for (int c = 0; c < 32; ++c) {
    s  += bf2f(pb[c * 2048]);
    ps += psumP[(b * 32 + c) * 4 + k];
  }
  out[idx] = s / ps;
}

extern "C" void kernel_launch(void* const* d_in, const int* in_sizes, int n_in,
                              void* d_out, int out_size, void* d_ws, size_t ws_size,
                              hipStream_t stream) {
  const float* x  = (const float*)d_in[0];
  const float* W1 = (const float*)d_in[1];
  const float* b1 = (const float*)d_in[2];
  const float* W3 = (const float*)d_in[3];
  const float* b3 = (const float*)d_in[4];
  const float* W2 = (const float*)d_in[5];
  // d_in[6] = b2: cancels in softmax; d_in[7] = bag_lengths: shapes only
  float* out = (float*)d_out;

  char* ws = (char*)d_ws;                         // ~4.73 MB used
  short* wc    = (short*)(ws + 0);                // 512 KB concat bf16 weights
  short* part  = (short*)(ws + 524288);           // 4 MB  [1024][4][512] bf16 partials
  float* psumP = (float*)(ws + 524288 + 4194304); // 16 KB [1024][4]

  hipLaunchKernelGGL(k_prep_w,   dim3(128), dim3(256), 0, stream, W1, W3, wc);
  hipLaunchKernelGGL(k_fused,    dim3(256), dim3(512), 0, stream, x, wc, b1, b3, W2, part, psumP);
  hipLaunchKernelGGL(k_finalize, dim3(256), dim3(256), 0, stream, part, psumP, out);
}

// Round 12
// 134.799 us; speedup vs baseline: 1.4608x; 1.4608x over previous
//
#include <hip/hip_runtime.h>
#include <hip/hip_bf16.h>

// MILAttentionPool: B=32, L=2048, D=512, H=256, K=4
// out[b, k*512+d] = sum_l softmax_l(logit[b,l,k]) * x[b*L+l, d]
// logit = (tanh(x@W1+b1)*sigmoid(x@W3+b3)) @ W2   (+b2 cancels in softmax)
//
// R12 = R10 + stage-latency hiding without register blowup:
//  512 persistent blocks x 2 tiles, single 64KB x-buffer.
//  Next tile's 16 float4 HBM loads are issued AFTER the epilogue barrier
//  (acc regs dead -> xf[16] fits under the 128-VGPR cap, no spill) and
//  consumed by the LDS write after pooling -> HBM latency hides under
//  logits+pool. GEMM/pool layouts identical to R10 (0 bank conflicts).

typedef short  bf16x8 __attribute__((ext_vector_type(8)));
typedef float  f32x4  __attribute__((ext_vector_type(4)));

#define D_IN    512
#define H_DIM   256
#define L_BAG   2048

__device__ __forceinline__ short f2bf(float f) {
  union { __hip_bfloat16 h; short s; } u;
  u.h = __float2bfloat16(f);
  return u.s;
}
__device__ __forceinline__ float bf2f(short s) {
  union { float f; unsigned u; } u;
  u.u = ((unsigned)(unsigned short)s) << 16;
  return u.f;
}

// ---------------- k0: concat-interleaved, chunk-major bf16 weights ----------------
// wc short idx = kt*16384 + (c*512 + n_c)*8 + r   (k = kt*32 + c*8 + r)
//   n_c: g=n_c>>5, j=n_c&31; j<16 -> W1[:, g*16+j] else W3[:, g*16+j-16]
__global__ __launch_bounds__(256) void k_prep_w(const float* __restrict__ W1,
                                                const float* __restrict__ W3,
                                                short* __restrict__ wc) {
  int t = blockIdx.x * 256 + threadIdx.x;   // 0..32767
  int n_c = t & 511;
  int kc  = t >> 9;            // k-chunk of 8: 0..63
  int kt = kc >> 2, c = kc & 3;
  int g = n_c >> 5, j = n_c & 31;
  const float* src = (j < 16) ? W1 : W3;
  int h = g * 16 + (j & 15);
  bf16x8 v;
  #pragma unroll
  for (int r = 0; r < 8; ++r) v[r] = f2bf(src[(kc * 8 + r) * H_DIM + h]);
  *(bf16x8*)(wc + kt * 16384 + (c * 512 + n_c) * 8) = v;
}

// ---------------- k1: persistent fused stage+GEMM+gate@W2+exp+pool ----------------
__global__ __launch_bounds__(512, 4) void k_fused(
    const float* __restrict__ x,
    const short* __restrict__ wc,
    const float* __restrict__ b1, const float* __restrict__ b3,
    const float* __restrict__ W2,
    short* __restrict__ part, float* __restrict__ psumP)
{
  __shared__ __align__(16) short xbf[64 * 512];     // 64 KB, chunk-major [kc][row][8]
  __shared__ float lpart[8][64][4];                 //  8 KB
  __shared__ __align__(16) float wlds[64 * 4];      //  1 KB
  __shared__ float psc[4][4];                       // (total ~73 KB -> 2 blocks/CU)

  const int tid  = threadIdx.x;
  const int lane = tid & 63;
  const int w    = tid >> 6;
  const int l15  = lane & 15;
  const int q    = lane >> 4;

  const int r   = tid & 63;         // staging row
  const int kc0 = (tid >> 6) * 8;   // staging k-chunk base

  float4 xf[16];                    // next-tile prefetch (statically indexed)

#define XLOAD(tile) { \
    const float* xr_ = x + ((long)(tile) * 64 + r) * D_IN + kc0 * 8; \
    _Pragma("unroll") \
    for (int j_ = 0; j_ < 8; ++j_) { \
      xf[2 * j_]     = ((const float4*)(xr_ + j_ * 8))[0]; \
      xf[2 * j_ + 1] = ((const float4*)(xr_ + j_ * 8))[1]; } }

#define XWRITE() { \
    _Pragma("unroll") \
    for (int j_ = 0; j_ < 8; ++j_) { bf16x8 v_; \
      v_[0] = f2bf(xf[2*j_].x);   v_[1] = f2bf(xf[2*j_].y); \
      v_[2] = f2bf(xf[2*j_].z);   v_[3] = f2bf(xf[2*j_].w); \
      v_[4] = f2bf(xf[2*j_+1].x); v_[5] = f2bf(xf[2*j_+1].y); \
      v_[6] = f2bf(xf[2*j_+1].z); v_[7] = f2bf(xf[2*j_+1].w); \
      *(bf16x8*)&xbf[((kc0 + j_) * 64 + r) * 8] = v_; } }

  const short* bgp = wc + (q * 512 + w * 64 + l15) * 8;

  bf16x8 bp0[2], bp1[2];
#define LDP0(kt) { const short* p_ = bgp + (kt) * 16384; \
    bp0[0] = *(const bf16x8*)(p_);       bp0[1] = *(const bf16x8*)(p_ + 128); }
#define LDP1(kt) { const short* p_ = bgp + (kt) * 16384; \
    bp1[0] = *(const bf16x8*)(p_ + 256); bp1[1] = *(const bf16x8*)(p_ + 384); }

  // ---- prologue: stage tile 0 ----
  XLOAD(blockIdx.x * 2);
  XWRITE();
  __syncthreads();

  #pragma unroll
  for (int t = 0; t < 2; ++t) {
    const int tile = blockIdx.x * 2 + t;

    // ---- GEMM: acc[mf 4][nf 4]; B from L2 as alternating 2-frag pairs ----
    f32x4 acc[4][4];
    #pragma unroll
    for (int mf = 0; mf < 4; ++mf)
      #pragma unroll
      for (int nf = 0; nf < 4; ++nf) acc[mf][nf] = (f32x4){0.f, 0.f, 0.f, 0.f};

    LDP0(0);
    #pragma unroll
    for (int kt = 0; kt < 16; ++kt) {
      LDP1(kt);
      const int ab = (kt * 4 + q) * 512 + l15 * 8;
      bf16x8 af[4];
      #pragma unroll
      for (int mf = 0; mf < 4; ++mf) af[mf] = *(const bf16x8*)&xbf[ab + mf * 128];
      #pragma unroll
      for (int mf = 0; mf < 4; ++mf) {
        acc[mf][0] = __builtin_amdgcn_mfma_f32_16x16x32_bf16(af[mf], bp0[0], acc[mf][0], 0, 0, 0);
        acc[mf][1] = __builtin_amdgcn_mfma_f32_16x16x32_bf16(af[mf], bp0[1], acc[mf][1], 0, 0, 0);
      }
      if (kt < 15) LDP0(kt + 1);
      #pragma unroll
      for (int mf = 0; mf < 4; ++mf) {
        acc[mf][2] = __builtin_amdgcn_mfma_f32_16x16x32_bf16(af[mf], bp1[0], acc[mf][2], 0, 0, 0);
        acc[mf][3] = __builtin_amdgcn_mfma_f32_16x16x32_bf16(af[mf], bp1[1], acc[mf][3], 0, 0, 0);
      }
    }

    // ---- epilogue: gate + @W2, per-mf ----
    {
      float b1v[2], b3v[2];
      f32x4 wv[2];
      #pragma unroll
      for (int p = 0; p < 2; ++p) {
        int h = w * 32 + p * 16 + l15;
        b1v[p] = b1[h];
        b3v[p] = b3[h];
        wv[p] = *(const f32x4*)&W2[h * 4];
      }
      #pragma unroll
      for (int mf = 0; mf < 4; ++mf) {
        float pl[4][4];
        #pragma unroll
        for (int j = 0; j < 4; ++j)
          #pragma unroll
          for (int kk = 0; kk < 4; ++kk) pl[j][kk] = 0.f;
        #pragma unroll
        for (int p = 0; p < 2; ++p)
          #pragma unroll
          for (int j = 0; j < 4; ++j) {
            float h1 = acc[mf][2 * p][j]     + b1v[p];
            float h3 = acc[mf][2 * p + 1][j] + b3v[p];
            float th = 1.f - __fdividef(2.f, __expf(2.f * h1) + 1.f);
            float sg = __fdividef(1.f, 1.f + __expf(-h3));
            float g = th * sg;
            pl[j][0] += g * wv[p][0];
            pl[j][1] += g * wv[p][1];
            pl[j][2] += g * wv[p][2];
            pl[j][3] += g * wv[p][3];
          }
        #pragma unroll
        for (int off = 1; off < 16; off <<= 1)
          #pragma unroll
          for (int j = 0; j < 4; ++j)
            #pragma unroll
            for (int kk = 0; kk < 4; ++kk)
              pl[j][kk] += __shfl_xor(pl[j][kk], off);
        if (l15 == 0) {
          #pragma unroll
          for (int j = 0; j < 4; ++j)
            #pragma unroll
            for (int kk = 0; kk < 4; ++kk)
              lpart[w][mf * 16 + q * 4 + j][kk] = pl[j][kk];
        }
      }
    }
    __syncthreads();   // lpart ready; acc dead

    // ---- prefetch next tile NOW (overlaps logits + pool; regs fit) ----
    if (t == 0) {
      XLOAD(tile + 1);
      __builtin_amdgcn_sched_barrier(0);
    }

    // ---- logits sum, exp (no max: logits ~N(0,0.3)), per-tile psum ----
    if (tid < 256) {
      const int rr = tid >> 2, kk = tid & 3;
      float lg = 0.f;
      #pragma unroll
      for (int ww = 0; ww < 8; ++ww) lg += lpart[ww][rr][kk];
      float e = __expf(lg);
      wlds[rr * 4 + kk] = e;
      float v = e;
      #pragma unroll
      for (int o = 4; o < 64; o <<= 1) v += __shfl_xor(v, o);
      if (lane < 4) psc[tid >> 6][lane] = v;   // lane == kk for lanes 0..3
    }
    __syncthreads();   // wlds + psc ready
    if (tid < 4) psumP[tile * 4 + tid] = psc[0][tid] + psc[1][tid] + psc[2][tid] + psc[3][tid];

    // ---- pooling from LDS (kc-rotated, conflict-free) ----
    {
      const int d  = tid;            // 0..511
      const int kc = d >> 3;
      const int e  = d & 7;
      const short* xcol = &xbf[kc * 512 + e];
      float a0 = 0.f, a1 = 0.f, a2 = 0.f, a3 = 0.f;
      #pragma unroll 8
      for (int ii = 0; ii < 64; ++ii) {
        int l = (ii + kc) & 63;
        float xv = bf2f(xcol[l * 8]);
        float4 wv4 = *(const float4*)&wlds[l * 4];
        a0 += wv4.x * xv; a1 += wv4.y * xv; a2 += wv4.z * xv; a3 += wv4.w * xv;
      }
      short* pp = part + (long)tile * 2048 + d;
      pp[0]    = f2bf(a0);
      pp[512]  = f2bf(a1);
      pp[1024] = f2bf(a2);
      pp[1536] = f2bf(a3);
    }

    if (t == 0) {
      __syncthreads();   // all pool reads of xbf done
      XWRITE();          // counted vmcnt wait on xf (issued ~2 us ago: free)
      __syncthreads();   // next tile staged
    }
  }
}

// ---------------- k2: reduce 32 chunks per bag, divide by sum(exp) ----------------
__global__ __launch_bounds__(256) void k_finalize(const short* __restrict__ part,
                                                  const float* __restrict__ psumP,
                                                  float* __restrict__ out) {
  int idx = blockIdx.x * 256 + threadIdx.x;   // b*2048 + k*512 + d
  int b = idx >> 11, k = (idx >> 9) & 3, d = idx & 511;
  const short* pb = part + ((long)b * 32) * 2048 + k * 512 + d;
  float s = 0.f, ps = 0.f;
  #pragma unroll
  for (int c = 0; c < 32; ++c) {
    s  += bf2f(pb[c * 2048]);
    ps += psumP[(b * 32 + c) * 4 + k];
  }
  out[idx] = s / ps;
}

extern "C" void kernel_launch(void* const* d_in, const int* in_sizes, int n_in,
                              void* d_out, int out_size, void* d_ws, size_t ws_size,
                              hipStream_t stream) {
  const float* x  = (const float*)d_in[0];
  const float* W1 = (const float*)d_in[1];
  const float* b1 = (const float*)d_in[2];
  const float* W3 = (const float*)d_in[3];
  const float* b3 = (const float*)d_in[4];
  const float* W2 = (const float*)d_in[5];
  // d_in[6] = b2: cancels in softmax; d_in[7] = bag_lengths: shapes only
  float* out = (float*)d_out;

  char* ws = (char*)d_ws;                         // ~4.73 MB used
  short* wc    = (short*)(ws + 0);                // 512 KB concat bf16 weights
  short* part  = (short*)(ws + 524288);           // 4 MB  [1024][4][512] bf16 partials
  float* psumP = (float*)(ws + 524288 + 4194304); // 16 KB [1024][4]

  hipLaunchKernelGGL(k_prep_w,   dim3(128), dim3(256), 0, stream, W1, W3, wc);
  hipLaunchKernelGGL(k_fused,    dim3(512), dim3(512), 0, stream, x, wc, b1, b3, W2, part, psumP);
  hipLaunchKernelGGL(k_finalize, dim3(256), dim3(256), 0, stream, part, psumP, out);
}

// Round 13
// 85.307 us; speedup vs baseline: 2.3084x; 1.5802x over previous
//
#include <hip/hip_runtime.h>
#include <hip/hip_bf16.h>

// MILAttentionPool: B=32, L=2048, D=512, H=256, K=4
// out[b, k*512+d] = sum_l softmax_l(logit[b,l,k]) * x[b*L+l, d]
// logit = (tanh(x@W1+b1)*sigmoid(x@W3+b3)) @ W2   (+b2 cancels in softmax)
//
// R13 = R8 fused structure + stage-latency overlap with NAMED prefetch regs
// (R11/R12 regressions were float4 xf[16] -> local-memory scratch, rule #20;
//  WRITE_SIZE 148-204MB was the smoking gun). 512 blocks x 2 tiles, all
// resident (2 blocks/CU). Next tile's loads issued after the epilogue
// barrier (acc dead), written to LDS after pool. GEMM = R8's proven loop;
// pool = R10's kc-rotation (0 conflicts).

typedef short  bf16x8 __attribute__((ext_vector_type(8)));
typedef float  f32x4  __attribute__((ext_vector_type(4)));

#define D_IN    512
#define H_DIM   256
#define L_BAG   2048

__device__ __forceinline__ short f2bf(float f) {
  union { __hip_bfloat16 h; short s; } u;
  u.h = __float2bfloat16(f);
  return u.s;
}
__device__ __forceinline__ float bf2f(short s) {
  union { float f; unsigned u; } u;
  u.u = ((unsigned)(unsigned short)s) << 16;
  return u.f;
}

// ---------------- k0: concat-interleaved, chunk-major bf16 weights ----------------
// wc short idx = kt*16384 + (c*512 + n_c)*8 + r   (k = kt*32 + c*8 + r)
//   n_c: g=n_c>>5, j=n_c&31; j<16 -> W1[:, g*16+j] else W3[:, g*16+j-16]
__global__ __launch_bounds__(256) void k_prep_w(const float* __restrict__ W1,
                                                const float* __restrict__ W3,
                                                short* __restrict__ wc) {
  int t = blockIdx.x * 256 + threadIdx.x;   // 0..32767
  int n_c = t & 511;
  int kc  = t >> 9;            // k-chunk of 8: 0..63
  int kt = kc >> 2, c = kc & 3;
  int g = n_c >> 5, j = n_c & 31;
  const float* src = (j < 16) ? W1 : W3;
  int h = g * 16 + (j & 15);
  bf16x8 v;
  #pragma unroll
  for (int r = 0; r < 8; ++r) v[r] = f2bf(src[(kc * 8 + r) * H_DIM + h]);
  *(bf16x8*)(wc + kt * 16384 + (c * 512 + n_c) * 8) = v;
}

// ---------------- k1: persistent fused stage+GEMM+gate@W2+exp+pool ----------------
__global__ __launch_bounds__(512, 4) void k_fused(
    const float* __restrict__ x,
    const short* __restrict__ wc,
    const float* __restrict__ b1, const float* __restrict__ b3,
    const float* __restrict__ W2,
    short* __restrict__ part, float* __restrict__ psumP)
{
  __shared__ __align__(16) short xbf[64 * 512];     // 64 KB, chunk-major [kc][row][8]
  __shared__ float lpart[8][64][4];                 //  8 KB
  __shared__ __align__(16) float wlds[64 * 4];      //  1 KB
  __shared__ float psc[4][4];                       // (total ~73 KB -> 2 blocks/CU)

  const int tid  = threadIdx.x;
  const int lane = tid & 63;
  const int w    = tid >> 6;
  const int l15  = lane & 15;
  const int q    = lane >> 4;

  const int r   = tid & 63;         // staging row
  const int kc0 = (tid >> 6) * 8;   // staging k-chunk base

  // NAMED prefetch registers (rule #20: arrays here go to scratch!)
  float4 xa0, xa1, xa2, xa3, xa4, xa5, xa6, xa7;
  float4 xb0, xb1, xb2, xb3, xb4, xb5, xb6, xb7;

#define XLOAD(tile) { \
    const float* xr_ = x + ((long)(tile) * 64 + r) * D_IN + kc0 * 8; \
    xa0 = ((const float4*)(xr_ +  0))[0];  xb0 = ((const float4*)(xr_ +  0))[1]; \
    xa1 = ((const float4*)(xr_ +  8))[0];  xb1 = ((const float4*)(xr_ +  8))[1]; \
    xa2 = ((const float4*)(xr_ + 16))[0];  xb2 = ((const float4*)(xr_ + 16))[1]; \
    xa3 = ((const float4*)(xr_ + 24))[0];  xb3 = ((const float4*)(xr_ + 24))[1]; \
    xa4 = ((const float4*)(xr_ + 32))[0];  xb4 = ((const float4*)(xr_ + 32))[1]; \
    xa5 = ((const float4*)(xr_ + 40))[0];  xb5 = ((const float4*)(xr_ + 40))[1]; \
    xa6 = ((const float4*)(xr_ + 48))[0];  xb6 = ((const float4*)(xr_ + 48))[1]; \
    xa7 = ((const float4*)(xr_ + 56))[0];  xb7 = ((const float4*)(xr_ + 56))[1]; }

#define XPACK(j_, A_, B_) { bf16x8 v_; \
    v_[0] = f2bf(A_.x); v_[1] = f2bf(A_.y); v_[2] = f2bf(A_.z); v_[3] = f2bf(A_.w); \
    v_[4] = f2bf(B_.x); v_[5] = f2bf(B_.y); v_[6] = f2bf(B_.z); v_[7] = f2bf(B_.w); \
    *(bf16x8*)&xbf[((kc0 + (j_)) * 64 + r) * 8] = v_; }

#define XWRITE() { \
    XPACK(0, xa0, xb0); XPACK(1, xa1, xb1); XPACK(2, xa2, xb2); XPACK(3, xa3, xb3); \
    XPACK(4, xa4, xb4); XPACK(5, xa5, xb5); XPACK(6, xa6, xb6); XPACK(7, xa7, xb7); }

  const short* bgp = wc + (q * 512 + w * 64 + l15) * 8;

  // ---- prologue: stage tile 0 ----
  XLOAD(blockIdx.x * 2);
  XWRITE();
  __syncthreads();

  #pragma unroll
  for (int t = 0; t < 2; ++t) {
    const int tile = blockIdx.x * 2 + t;

    // ---- GEMM (R8's proven loop): acc[mf 4][nf 4]; B per-lane from L2 ----
    f32x4 acc[4][4];
    #pragma unroll
    for (int mf = 0; mf < 4; ++mf)
      #pragma unroll
      for (int nf = 0; nf < 4; ++nf) acc[mf][nf] = (f32x4){0.f, 0.f, 0.f, 0.f};

    #pragma unroll 1
    for (int kt = 0; kt < 16; ++kt) {
      bf16x8 af[4], bfr[4];
      const short* bk = bgp + kt * 16384;
      #pragma unroll
      for (int nf = 0; nf < 4; ++nf)
        bfr[nf] = *(const bf16x8*)(bk + nf * 128);
      const int ab = (kt * 4 + q) * 512 + l15 * 8;
      #pragma unroll
      for (int mf = 0; mf < 4; ++mf)
        af[mf] = *(const bf16x8*)&xbf[ab + mf * 128];
      #pragma unroll
      for (int mf = 0; mf < 4; ++mf)
        #pragma unroll
        for (int nf = 0; nf < 4; ++nf)
          acc[mf][nf] = __builtin_amdgcn_mfma_f32_16x16x32_bf16(af[mf], bfr[nf], acc[mf][nf], 0, 0, 0);
    }

    // ---- epilogue: gate + @W2, per-mf ----
    {
      float b1v[2], b3v[2];
      f32x4 wv[2];
      #pragma unroll
      for (int p = 0; p < 2; ++p) {
        int h = w * 32 + p * 16 + l15;
        b1v[p] = b1[h];
        b3v[p] = b3[h];
        wv[p] = *(const f32x4*)&W2[h * 4];
      }
      #pragma unroll
      for (int mf = 0; mf < 4; ++mf) {
        float pl[4][4];
        #pragma unroll
        for (int j = 0; j < 4; ++j)
          #pragma unroll
          for (int kk = 0; kk < 4; ++kk) pl[j][kk] = 0.f;
        #pragma unroll
        for (int p = 0; p < 2; ++p)
          #pragma unroll
          for (int j = 0; j < 4; ++j) {
            float h1 = acc[mf][2 * p][j]     + b1v[p];
            float h3 = acc[mf][2 * p + 1][j] + b3v[p];
            float th = 1.f - __fdividef(2.f, __expf(2.f * h1) + 1.f);
            float sg = __fdividef(1.f, 1.f + __expf(-h3));
            float g = th * sg;
            pl[j][0] += g * wv[p][0];
            pl[j][1] += g * wv[p][1];
            pl[j][2] += g * wv[p][2];
            pl[j][3] += g * wv[p][3];
          }
        #pragma unroll
        for (int off = 1; off < 16; off <<= 1)
          #pragma unroll
          for (int j = 0; j < 4; ++j)
            #pragma unroll
            for (int kk = 0; kk < 4; ++kk)
              pl[j][kk] += __shfl_xor(pl[j][kk], off);
        if (l15 == 0) {
          #pragma unroll
          for (int j = 0; j < 4; ++j)
            #pragma unroll
            for (int kk = 0; kk < 4; ++kk)
              lpart[w][mf * 16 + q * 4 + j][kk] = pl[j][kk];
        }
      }
    }
    __syncthreads();   // lpart ready; acc dead

    // ---- issue next tile's HBM loads NOW (named regs; overlaps logits+pool) ----
    if (t == 0) XLOAD(tile + 1);

    // ---- logits sum, exp (no max: logits ~N(0,0.3)), per-tile psum ----
    if (tid < 256) {
      const int rr = tid >> 2, kk = tid & 3;
      float lg = 0.f;
      #pragma unroll
      for (int ww = 0; ww < 8; ++ww) lg += lpart[ww][rr][kk];
      float e = __expf(lg);
      wlds[rr * 4 + kk] = e;
      float v = e;
      #pragma unroll
      for (int o = 4; o < 64; o <<= 1) v += __shfl_xor(v, o);
      if (lane < 4) psc[tid >> 6][lane] = v;   // lane == kk for lanes 0..3
    }
    __syncthreads();   // wlds + psc ready
    if (tid < 4) psumP[tile * 4 + tid] = psc[0][tid] + psc[1][tid] + psc[2][tid] + psc[3][tid];

    // ---- pooling from LDS (kc-rotated, conflict-free) ----
    {
      const int d  = tid;            // 0..511
      const int kc = d >> 3;
      const int e  = d & 7;
      const short* xcol = &xbf[kc * 512 + e];
      float a0 = 0.f, a1 = 0.f, a2 = 0.f, a3 = 0.f;
      #pragma unroll 8
      for (int ii = 0; ii < 64; ++ii) {
        int l = (ii + kc) & 63;
        float xv = bf2f(xcol[l * 8]);
        float4 wv4 = *(const float4*)&wlds[l * 4];
        a0 += wv4.x * xv; a1 += wv4.y * xv; a2 += wv4.z * xv; a3 += wv4.w * xv;
      }
      short* pp = part + (long)tile * 2048 + d;
      pp[0]    = f2bf(a0);
      pp[512]  = f2bf(a1);
      pp[1024] = f2bf(a2);
      pp[1536] = f2bf(a3);
    }

    if (t == 0) {
      __syncthreads();   // all pool reads of xbf done
      XWRITE();          // loads issued ~2 us ago: vmcnt wait ~free
      __syncthreads();   // next tile staged
    }
  }
}

// ---------------- k2: reduce 32 chunks per bag, divide by sum(exp) ----------------
__global__ __launch_bounds__(256) void k_finalize(const short* __restrict__ part,
                                                  const float* __restrict__ psumP,
                                                  float* __restrict__ out) {
  int idx = blockIdx.x * 256 + threadIdx.x;   // b*2048 + k*512 + d
  int b = idx >> 11, k = (idx >> 9) & 3, d = idx & 511;
  const short* pb = part + ((long)b * 32) * 2048 + k * 512 + d;
  float s = 0.f, ps = 0.f;
  #pragma unroll
  for (int c = 0; c < 32; ++c) {
    s  += bf2f(pb[c * 2048]);
    ps += psumP[(b * 32 + c) * 4 + k];
  }
  out[idx] = s / ps;
}

extern "C" void kernel_launch(void* const* d_in, const int* in_sizes, int n_in,
                              void* d_out, int out_size, void* d_ws, size_t ws_size,
                              hipStream_t stream) {
  const float* x  = (const float*)d_in[0];
  const float* W1 = (const float*)d_in[1];
  const float* b1 = (const float*)d_in[2];
  const float* W3 = (const float*)d_in[3];
  const float* b3 = (const float*)d_in[4];
  const float* W2 = (const float*)d_in[5];
  // d_in[6] = b2: cancels in softmax; d_in[7] = bag_lengths: shapes only
  float* out = (float*)d_out;

  char* ws = (char*)d_ws;                         // ~4.73 MB used
  short* wc    = (short*)(ws + 0);                // 512 KB concat bf16 weights
  short* part  = (short*)(ws + 524288);           // 4 MB  [1024][4][512] bf16 partials
  float* psumP = (float*)(ws + 524288 + 4194304); // 16 KB [1024][4]

  hipLaunchKernelGGL(k_prep_w,   dim3(128), dim3(256), 0, stream, W1, W3, wc);
  hipLaunchKernelGGL(k_fused,    dim3(512), dim3(512), 0, stream, x, wc, b1, b3, W2, part, psumP);
  hipLaunchKernelGGL(k_finalize, dim3(256), dim3(256), 0, stream, part, psumP, out);
}

// Round 14
// 78.686 us; speedup vs baseline: 2.5026x; 1.0841x over previous
//
#include <hip/hip_runtime.h>
#include <hip/hip_bf16.h>

// MILAttentionPool: B=32, L=2048, D=512, H=256, K=4
// out[b, k*512+d] = sum_l softmax_l(logit[b,l,k]) * x[b*L+l, d]
// logit = (tanh(x@W1+b1)*sigmoid(x@W3+b3)) @ W2   (+b2 cancels in softmax)
//
// R14 = R8 skeleton (1024 blocks x 1 tile, best measured: 81.4us) with
// R10's conflict-free layouts (chunk-major stride-512 + kc-rotation pool)
// and VALU cuts (VALU is the measured dominant pipe: ~26% busy, no other
// pipe >12%):
//  - manual RNE fp32->bf16 (3 ops; inputs finite, no NaN path needed)
//  - gate = (A-1)*rcp((A+1)*(1+B)), A=e^{2h1}, B=e^{-h3}: 1 v_rcp total
//  - no B-prefetch pairs (R10 showed they cost ~5us vs R8's plain loop)

typedef short  bf16x8 __attribute__((ext_vector_type(8)));
typedef float  f32x4  __attribute__((ext_vector_type(4)));

#define D_IN    512
#define H_DIM   256
#define L_BAG   2048

// manual round-to-nearest-even fp32->bf16 (finite inputs only)
__device__ __forceinline__ short f2bf(float f) {
  union { float f; unsigned u; } u;
  u.f = f;
  unsigned r = u.u + 0x7FFFu + ((u.u >> 16) & 1u);
  return (short)(r >> 16);
}
__device__ __forceinline__ float bf2f(short s) {
  union { float f; unsigned u; } u;
  u.u = ((unsigned)(unsigned short)s) << 16;
  return u.f;
}

// ---------------- k0: concat-interleaved, chunk-major bf16 weights ----------------
// wc short idx = kt*16384 + (c*512 + n_c)*8 + r   (k = kt*32 + c*8 + r)
//   n_c: g=n_c>>5, j=n_c&31; j<16 -> W1[:, g*16+j] else W3[:, g*16+j-16]
__global__ __launch_bounds__(256) void k_prep_w(const float* __restrict__ W1,
                                                const float* __restrict__ W3,
                                                short* __restrict__ wc) {
  int t = blockIdx.x * 256 + threadIdx.x;   // 0..32767
  int n_c = t & 511;
  int kc  = t >> 9;            // k-chunk of 8: 0..63
  int kt = kc >> 2, c = kc & 3;
  int g = n_c >> 5, j = n_c & 31;
  const float* src = (j < 16) ? W1 : W3;
  int h = g * 16 + (j & 15);
  bf16x8 v;
  #pragma unroll
  for (int r = 0; r < 8; ++r) v[r] = f2bf(src[(kc * 8 + r) * H_DIM + h]);
  *(bf16x8*)(wc + kt * 16384 + (c * 512 + n_c) * 8) = v;
}

// ---------------- k1: fused stage + GEMM + gate@W2 + exp + pool ----------------
// 512 thr = 8 waves; wave w owns concat cols [w*64, w*64+64) (= H cols [w*32,+32)).
__global__ __launch_bounds__(512, 4) void k_fused(
    const float* __restrict__ x,
    const short* __restrict__ wc,
    const float* __restrict__ b1, const float* __restrict__ b3,
    const float* __restrict__ W2,
    short* __restrict__ part, float* __restrict__ psumP)
{
  __shared__ __align__(16) short xbf[64 * 512];     // 64 KB, chunk-major [kc][row][8]
  __shared__ float lpart[8][64][4];                 //  8 KB
  __shared__ __align__(16) float wlds[64 * 4];      //  1 KB
  __shared__ float psc[4][4];                       // (total ~73 KB -> 2 blocks/CU)

  const int tid  = threadIdx.x;
  const int lane = tid & 63;
  const int w    = tid >> 6;
  const int l15  = lane & 15;
  const int q    = lane >> 4;
  const int blk  = blockIdx.x;
  const long row0 = (long)blk * 64;

  // ---- stage x tile: 64 rows x 512 k, fp32 -> bf16, chunk-major ----
  {
    const int r   = tid & 63;
    const int kc0 = (tid >> 6) * 8;
    const float* xr = x + (row0 + r) * D_IN + kc0 * 8;
    #pragma unroll
    for (int j = 0; j < 8; ++j) {
      float4 f0 = ((const float4*)(xr + j * 8))[0];
      float4 f1 = ((const float4*)(xr + j * 8))[1];
      bf16x8 v;
      v[0] = f2bf(f0.x); v[1] = f2bf(f0.y); v[2] = f2bf(f0.z); v[3] = f2bf(f0.w);
      v[4] = f2bf(f1.x); v[5] = f2bf(f1.y); v[6] = f2bf(f1.z); v[7] = f2bf(f1.w);
      *(bf16x8*)&xbf[((kc0 + j) * 64 + r) * 8] = v;   // consecutive lanes contiguous
    }
  }
  __syncthreads();

  // ---- GEMM: acc[mf 4][nf 4]; B per-lane from L2 (plain loop, R8-style) ----
  f32x4 acc[4][4];
  #pragma unroll
  for (int mf = 0; mf < 4; ++mf)
    #pragma unroll
    for (int nf = 0; nf < 4; ++nf) acc[mf][nf] = (f32x4){0.f, 0.f, 0.f, 0.f};

  const short* bgp = wc + (q * 512 + w * 64 + l15) * 8;

  #pragma unroll 1
  for (int kt = 0; kt < 16; ++kt) {
    bf16x8 af[4], bfr[4];
    const short* bk = bgp + kt * 16384;
    #pragma unroll
    for (int nf = 0; nf < 4; ++nf)
      bfr[nf] = *(const bf16x8*)(bk + nf * 128);
    const int ab = (kt * 4 + q) * 512 + l15 * 8;
    #pragma unroll
    for (int mf = 0; mf < 4; ++mf)
      af[mf] = *(const bf16x8*)&xbf[ab + mf * 128];
    #pragma unroll
    for (int mf = 0; mf < 4; ++mf)
      #pragma unroll
      for (int nf = 0; nf < 4; ++nf)
        acc[mf][nf] = __builtin_amdgcn_mfma_f32_16x16x32_bf16(af[mf], bfr[nf], acc[mf][nf], 0, 0, 0);
  }

  // ---- epilogue: gate + @W2, per-mf to limit register pressure ----
  float b1v[2], b3v[2];
  f32x4 wv[2];
  #pragma unroll
  for (int p = 0; p < 2; ++p) {
    int h = w * 32 + p * 16 + l15;
    b1v[p] = b1[h];
    b3v[p] = b3[h];
    wv[p] = *(const f32x4*)&W2[h * 4];
  }
  #pragma unroll
  for (int mf = 0; mf < 4; ++mf) {
    float pl[4][4];
    #pragma unroll
    for (int j = 0; j < 4; ++j)
      #pragma unroll
      for (int kk = 0; kk < 4; ++kk) pl[j][kk] = 0.f;
    #pragma unroll
    for (int p = 0; p < 2; ++p)
      #pragma unroll
      for (int j = 0; j < 4; ++j) {
        float h1 = acc[mf][2 * p][j]     + b1v[p];
        float h3 = acc[mf][2 * p + 1][j] + b3v[p];
        // g = tanh(h1)*sigmoid(h3) = (A-1) / ((A+1)*(1+B)), A=e^{2h1}, B=e^{-h3}
        float A = __expf(2.f * h1);
        float B = __expf(-h3);
        float g = (A - 1.f) * __builtin_amdgcn_rcpf((A + 1.f) * (1.f + B));
        pl[j][0] += g * wv[p][0];
        pl[j][1] += g * wv[p][1];
        pl[j][2] += g * wv[p][2];
        pl[j][3] += g * wv[p][3];
      }
    #pragma unroll
    for (int off = 1; off < 16; off <<= 1)
      #pragma unroll
      for (int j = 0; j < 4; ++j)
        #pragma unroll
        for (int kk = 0; kk < 4; ++kk)
          pl[j][kk] += __shfl_xor(pl[j][kk], off);
    if (l15 == 0) {
      #pragma unroll
      for (int j = 0; j < 4; ++j)
        #pragma unroll
        for (int kk = 0; kk < 4; ++kk)
          lpart[w][mf * 16 + q * 4 + j][kk] = pl[j][kk];
    }
  }
  __syncthreads();

  // ---- logits sum across waves, exp (no max: logits ~N(0,0.3)), per-block psum ----
  if (tid < 256) {
    const int r = tid >> 2, kk = tid & 3;
    float lg = 0.f;
    #pragma unroll
    for (int ww = 0; ww < 8; ++ww) lg += lpart[ww][r][kk];
    float e = __expf(lg);
    wlds[r * 4 + kk] = e;
    float v = e;
    #pragma unroll
    for (int o = 4; o < 64; o <<= 1) v += __shfl_xor(v, o);
    if (lane < 4) psc[tid >> 6][lane] = v;   // lane == kk for lanes 0..3
  }
  __syncthreads();
  if (tid < 4) psumP[blk * 4 + tid] = psc[0][tid] + psc[1][tid] + psc[2][tid] + psc[3][tid];

  // ---- pooling from LDS, kc-rotated row order (conflict-free, no pad) ----
  {
    const int d  = tid;            // 0..511
    const int kc = d >> 3;
    const int e  = d & 7;
    const short* xcol = &xbf[kc * 512 + e];
    float a0 = 0.f, a1 = 0.f, a2 = 0.f, a3 = 0.f;
    #pragma unroll 8
    for (int ii = 0; ii < 64; ++ii) {
      int l = (ii + kc) & 63;                       // rotation: wave hits all 32 banks
      float xf = bf2f(xcol[l * 8]);
      float4 wv4 = *(const float4*)&wlds[l * 4];
      a0 += wv4.x * xf; a1 += wv4.y * xf; a2 += wv4.z * xf; a3 += wv4.w * xf;
    }
    short* pp = part + (long)blk * 2048 + d;
    pp[0]    = f2bf(a0);
    pp[512]  = f2bf(a1);
    pp[1024] = f2bf(a2);
    pp[1536] = f2bf(a3);
  }
}

// ---------------- k2: reduce 32 chunks per bag, divide by sum(exp) ----------------
__global__ __launch_bounds__(256) void k_finalize(const short* __restrict__ part,
                                                  const float* __restrict__ psumP,
                                                  float* __restrict__ out) {
  int idx = blockIdx.x * 256 + threadIdx.x;   // b*2048 + k*512 + d
  int b = idx >> 11, k = (idx >> 9) & 3, d = idx & 511;
  const short* pb = part + ((long)b * 32) * 2048 + k * 512 + d;
  float s = 0.f, ps = 0.f;
  #pragma unroll
  for (int c = 0; c < 32; ++c) {
    s  += bf2f(pb[c * 2048]);
    ps += psumP[(b * 32 + c) * 4 + k];
  }
  out[idx] = s / ps;
}

extern "C" void kernel_launch(void* const* d_in, const int* in_sizes, int n_in,
                              void* d_out, int out_size, void* d_ws, size_t ws_size,
                              hipStream_t stream) {
  const float* x  = (const float*)d_in[0];
  const float* W1 = (const float*)d_in[1];
  const float* b1 = (const float*)d_in[2];
  const float* W3 = (const float*)d_in[3];
  const float* b3 = (const float*)d_in[4];
  const float* W2 = (const float*)d_in[5];
  // d_in[6] = b2: cancels in softmax; d_in[7] = bag_lengths: shapes only
  float* out = (float*)d_out;

  char* ws = (char*)d_ws;                         // ~4.73 MB used
  short* wc    = (short*)(ws + 0);                // 512 KB concat bf16 weights
  short* part  = (short*)(ws + 524288);           // 4 MB  [1024][4][512] bf16 partials
  float* psumP = (float*)(ws + 524288 + 4194304); // 16 KB [1024][4]

  hipLaunchKernelGGL(k_prep_w,   dim3(128),  dim3(256), 0, stream, W1, W3, wc);
  hipLaunchKernelGGL(k_fused,    dim3(1024), dim3(512), 0, stream, x, wc, b1, b3, W2, part, psumP);
  hipLaunchKernelGGL(k_finalize, dim3(256),  dim3(256), 0, stream, part, psumP, out);
}